// Round 4
// baseline (2440.416 us; speedup 1.0000x reference)
//
#include <hip/hip_runtime.h>

#define N_NODES 100000
#define F 64
#define C 32
#define KH 3
#define E 1600000
#define NE (KH * E)                         // 4,800,000 edges

#define RPB 256                             // rows per bucket (row >> 8)
#define NBUCK ((N_NODES + RPB - 1) / RPB)   // 391
#define NSLICE 4                            // col slices; y-slice = 3.2 MB < 4 MB L2/XCD
#define SLICEW 25000                        // cols per slice
#define NBIN (NBUCK * NSLICE)               // 1564
#define ECH 1024                            // edges staged per spmm inner iter

// ---------------------------------------------------------------------------
// K1: y[n, c] = sum_f x[n, f] * W[f, c]   (all fp32)
// ---------------------------------------------------------------------------
__global__ __launch_bounds__(256) void gemm_xw(const float* __restrict__ x,
                                               const float* __restrict__ W,
                                               float* __restrict__ y) {
    __shared__ float Ws[F * C];  // 8 KB
    for (int i = threadIdx.x; i < F * C; i += 256) Ws[i] = W[i];
    __syncthreads();

    const int node = blockIdx.x * 256 + threadIdx.x;
    if (node >= N_NODES) return;

    const float4* xp = (const float4*)(x + (size_t)node * F);
    float acc[C];
#pragma unroll
    for (int c = 0; c < C; c++) acc[c] = 0.f;

#pragma unroll
    for (int i = 0; i < 16; i++) {
        float4 v = xp[i];
        const int f = i * 4;
#pragma unroll
        for (int c = 0; c < C; c++) {
            acc[c] += v.x * Ws[(f + 0) * C + c];
            acc[c] += v.y * Ws[(f + 1) * C + c];
            acc[c] += v.z * Ws[(f + 2) * C + c];
            acc[c] += v.w * Ws[(f + 3) * C + c];
        }
    }

    float4* yo = (float4*)(y + (size_t)node * C);
#pragma unroll
    for (int i = 0; i < 8; i++)
        yo[i] = make_float4(acc[4 * i], acc[4 * i + 1], acc[4 * i + 2], acc[4 * i + 3]);
}

// ---------------------------------------------------------------------------
// K2: 2D histogram — edges per (row-bucket, col-slice) bin.
// ---------------------------------------------------------------------------
__global__ __launch_bounds__(256) void hist2_k(const int* __restrict__ rows,
                                               const int* __restrict__ cols,
                                               int* __restrict__ hcnt) {
    const int e = blockIdx.x * 256 + threadIdx.x;
    if (e >= NE) return;
    const int bin = (rows[e] >> 8) * NSLICE + cols[e] / SLICEW;
    atomicAdd(&hcnt[bin], 1);
}

// ---------------------------------------------------------------------------
// K3: exclusive scan of 1564 bin counts (single block, padded to 2048).
// Writes gstart[0..NBIN] (sentinel NE) and gcur = gstart.
// ---------------------------------------------------------------------------
__global__ __launch_bounds__(256) void scan2_k(const int* __restrict__ hcnt,
                                               int* __restrict__ gstart,
                                               int* __restrict__ gcur) {
    __shared__ int sA[2048];
    __shared__ int sB[2048];
    const int tid = threadIdx.x;
    for (int i = tid; i < 2048; i += 256) sA[i] = (i < NBIN) ? hcnt[i] : 0;
    __syncthreads();

    int* src = sA;
    int* dst = sB;
    for (int d = 1; d < 2048; d <<= 1) {   // 11 rounds, result ends in src
        for (int i = tid; i < 2048; i += 256) {
            int v = src[i];
            if (i >= d) v += src[i - d];
            dst[i] = v;
        }
        __syncthreads();
        int* t = src; src = dst; dst = t;
    }
    for (int i = tid; i < NBIN; i += 256) {
        const int excl = (i == 0) ? 0 : src[i - 1];
        gstart[i] = excl;
        gcur[i] = excl;
    }
    if (tid == 0) gstart[NBIN] = NE;
}

// ---------------------------------------------------------------------------
// K4: partition — per-edge atomic claim into its bin's stream + direct 8B
// store. 1564 streams => ~100 KB of open lines chip-wide: L2 merges the
// partial-line writes (unlike the 100K-stream bucket_k, which thrashed).
// Entry: { (row & 255) << 17 | col , val*alpha } (8 B; col < 2^17).
// ---------------------------------------------------------------------------
__global__ __launch_bounds__(256) void part2_k(const float* __restrict__ vals,
                                               const int* __restrict__ rows,
                                               const int* __restrict__ cols,
                                               const float* __restrict__ alpha,
                                               int* __restrict__ gcur,
                                               int2* __restrict__ edgebuf) {
    const int e = blockIdx.x * 256 + threadIdx.x;
    if (e >= NE) return;
    const int r = rows[e];
    const int cl = cols[e];
    const int k = (e >= 2 * E) ? 2 : (e >= E) ? 1 : 0;
    const float w = vals[e] * alpha[k];
    const int bin = (r >> 8) * NSLICE + cl / SLICEW;
    const int pos = atomicAdd(&gcur[bin], 1);
    edgebuf[pos] = make_int2(((r & (RPB - 1)) << 17) | cl, __float_as_int(w));
}

// ---------------------------------------------------------------------------
// K5: SpMM — one block per (row-bucket, col-slice) bin. s = blockIdx & 3 so
// that under round-robin blockIdx->XCD mapping, all blocks resident on an XCD
// gather from the SAME 3.2 MB y-slice -> L2-resident gathers.
// 256x32 fp32 accumulator in LDS; 4 gathers in flight per half-wave.
// Merge across the 4 slices via contiguous-burst atomics into pre-zeroed out.
// ---------------------------------------------------------------------------
__global__ __launch_bounds__(256) void spmm2_k(const int2* __restrict__ edgebuf,
                                               const int* __restrict__ gstart,
                                               const float* __restrict__ y,
                                               float* __restrict__ out) {
    __shared__ float lacc[RPB * C];  // 32 KB
    __shared__ int2 sedge[ECH];      // 8 KB

    const int tid = threadIdx.x;
    const int s = blockIdx.x & (NSLICE - 1);
    const int b = blockIdx.x >> 2;
    const int bin = b * NSLICE + s;
    const int st = gstart[bin];
    const int n = gstart[bin + 1] - st;

    for (int i = tid; i < RPB * C; i += 256) lacc[i] = 0.f;

    const int hw = tid >> 5;  // 8 half-waves
    const int c = tid & 31;

    for (int bb = 0; bb < n; bb += ECH) {
        const int m = min(ECH, n - bb);
        __syncthreads();  // protects sedge (and lacc zero on first iter)
        for (int i = tid; i < m; i += 256) sedge[i] = edgebuf[st + bb + i];
        __syncthreads();

        int i = hw;
        for (; i + 24 < m; i += 32) {  // 4 gathers in flight per half-wave
            const int2 e0 = sedge[i];
            const int2 e1 = sedge[i + 8];
            const int2 e2 = sedge[i + 16];
            const int2 e3 = sedge[i + 24];
            const float y0 = y[(e0.x & 0x1FFFF) * C + c];
            const float y1 = y[(e1.x & 0x1FFFF) * C + c];
            const float y2 = y[(e2.x & 0x1FFFF) * C + c];
            const float y3 = y[(e3.x & 0x1FFFF) * C + c];
            atomicAdd(&lacc[((e0.x >> 17) << 5) + c], __int_as_float(e0.y) * y0);
            atomicAdd(&lacc[((e1.x >> 17) << 5) + c], __int_as_float(e1.y) * y1);
            atomicAdd(&lacc[((e2.x >> 17) << 5) + c], __int_as_float(e2.y) * y2);
            atomicAdd(&lacc[((e3.x >> 17) << 5) + c], __int_as_float(e3.y) * y3);
        }
        for (; i < m; i += 8) {
            const int2 e0 = sedge[i];
            const float y0 = y[(e0.x & 0x1FFFF) * C + c];
            atomicAdd(&lacc[((e0.x >> 17) << 5) + c], __int_as_float(e0.y) * y0);
        }
    }
    __syncthreads();

    if (n == 0) return;  // out is pre-zeroed; nothing to merge

    const int obase = b * RPB * C;
#pragma unroll
    for (int q = 0; q < (RPB * C) / 256; q++) {  // 32 contiguous 1KB bursts
        const int fi = q * 256 + tid;
        if (obase + fi < N_NODES * C) {
            const float v = lacc[fi];
            unsafeAtomicAdd(out + obase + fi, v);
        }
    }
}

// ---------------------------------------------------------------------------
// K6: out += bias (out holds the merged accumulator)
// ---------------------------------------------------------------------------
__global__ __launch_bounds__(256) void finalize_k(float* __restrict__ out,
                                                  const float* __restrict__ bias) {
    const int idx = (blockIdx.x * 256 + threadIdx.x) * 4;
    if (idx >= N_NODES * C) return;
    const int c0 = idx & (C - 1);
    float4 v = *(float4*)(out + idx);
    v.x += bias[c0 + 0];
    v.y += bias[c0 + 1];
    v.z += bias[c0 + 2];
    v.w += bias[c0 + 3];
    *(float4*)(out + idx) = v;
}

// ---------------------------------------------------------------------------
// Fallback path (atomic scatter) if workspace is too small.
// ---------------------------------------------------------------------------
__global__ __launch_bounds__(256) void scatter_edges(
    const float* __restrict__ vals, const int* __restrict__ rows,
    const int* __restrict__ cols, const float* __restrict__ alpha,
    const float* __restrict__ y, float* __restrict__ out_acc) {
    const int t = blockIdx.x * 256 + threadIdx.x;
    const int e = t >> 5;
    const int c = t & 31;
    if (e >= KH * E) return;
    const int k = (e >= 2 * E) ? 2 : (e >= E) ? 1 : 0;

    const float w = vals[e] * alpha[k];
    const int row = rows[e];
    const int col = cols[e];

    const float yv = y[(size_t)col * C + c];
    unsafeAtomicAdd(out_acc + (size_t)row * C + c, w * yv);
}

// ---------------------------------------------------------------------------
extern "C" void kernel_launch(void* const* d_in, const int* in_sizes, int n_in,
                              void* d_out, int out_size, void* d_ws, size_t ws_size,
                              hipStream_t stream) {
    const float* x         = (const float*)d_in[0];
    const float* edge_vals = (const float*)d_in[1];
    const float* W         = (const float*)d_in[2];
    const float* b         = (const float*)d_in[3];
    const float* alpha     = (const float*)d_in[4];
    const int*   edge_rows = (const int*)d_in[5];
    const int*   edge_cols = (const int*)d_in[6];
    float*       out       = (float*)d_out;

    // Workspace layout
    const size_t offY      = 0;                              // 12,800,000 B
    const size_t offEB     = (size_t)N_NODES * C * 4;        // edgebuf: 38,400,000 B
    const size_t offHist   = offEB + (size_t)NE * 8;         // 51,200,000
    const size_t offGstart = offHist + ((NBIN * 4 + 255) & ~(size_t)255);
    const size_t offGcur   = offGstart + (((NBIN + 1) * 4 + 255) & ~(size_t)255);
    const size_t need      = offGcur + (size_t)NBIN * 4;     // ~51.21 MB

    float* y = (float*)((char*)d_ws + offY);

    gemm_xw<<<(N_NODES + 255) / 256, 256, 0, stream>>>(x, W, y);

    if (ws_size >= need) {
        int2* edgebuf = (int2*)((char*)d_ws + offEB);
        int*  hcnt    = (int*)((char*)d_ws + offHist);
        int*  gstart  = (int*)((char*)d_ws + offGstart);
        int*  gcur    = (int*)((char*)d_ws + offGcur);

        hipMemsetAsync(out, 0, (size_t)N_NODES * C * sizeof(float), stream);
        hipMemsetAsync(hcnt, 0, (size_t)NBIN * 4, stream);

        const int eblocks = (NE + 255) / 256;  // 18750
        hist2_k<<<eblocks, 256, 0, stream>>>(edge_rows, edge_cols, hcnt);
        scan2_k<<<1, 256, 0, stream>>>(hcnt, gstart, gcur);
        part2_k<<<eblocks, 256, 0, stream>>>(edge_vals, edge_rows, edge_cols,
                                             alpha, gcur, edgebuf);
        spmm2_k<<<NBIN, 256, 0, stream>>>(edgebuf, gstart, y, out);
        finalize_k<<<(N_NODES * C / 4 + 255) / 256, 256, 0, stream>>>(out, b);
    } else {
        // Fallback: atomic scatter path
        hipMemsetAsync(out, 0, (size_t)N_NODES * C * sizeof(float), stream);
        const long long scatter_threads = (long long)KH * E * C;
        const int scatter_blocks = (int)((scatter_threads + 255) / 256);
        scatter_edges<<<scatter_blocks, 256, 0, stream>>>(
            edge_vals, edge_rows, edge_cols, alpha, y, out);
        finalize_k<<<(N_NODES * C / 4 + 255) / 256, 256, 0, stream>>>(out, b);
    }
}

// Round 5
// 592.459 us; speedup vs baseline: 4.1191x; 4.1191x over previous
//
#include <hip/hip_runtime.h>

#define N_NODES 100000
#define F 64
#define C 32
#define KH 3
#define E 1600000
#define NE (KH * E)                        // 4,800,000 edges

#define NSLICE 4                           // y col-slices; 3.2 MB < 4 MB L2/XCD
#define SLICEW 25000
#define NKEY (N_NODES * NSLICE)            // 400,000 sort keys (row*4 + slice)
#define KPB 512                            // keys per coarse bucket (= 128 rows)
#define NBUCK ((NKEY + KPB - 1) / KPB)     // 782
#define CHUNK 4096                         // edges per part1 block
#define EPT (CHUNK / 256)
#define NCHUNK ((NE + CHUNK - 1) / CHUNK)  // 1172
#define P2CAP 8192                         // part2 LDS capacity (mean 6144, sigma 78)

// ---------------------------------------------------------------------------
// K1: y[n, c] = sum_f x[n, f] * W[f, c]
// ---------------------------------------------------------------------------
__global__ __launch_bounds__(256) void gemm_xw(const float* __restrict__ x,
                                               const float* __restrict__ W,
                                               float* __restrict__ y) {
    __shared__ float Ws[F * C];
    for (int i = threadIdx.x; i < F * C; i += 256) Ws[i] = W[i];
    __syncthreads();

    const int node = blockIdx.x * 256 + threadIdx.x;
    if (node >= N_NODES) return;

    const float4* xp = (const float4*)(x + (size_t)node * F);
    float acc[C];
#pragma unroll
    for (int c = 0; c < C; c++) acc[c] = 0.f;

#pragma unroll
    for (int i = 0; i < 16; i++) {
        float4 v = xp[i];
        const int f = i * 4;
#pragma unroll
        for (int c = 0; c < C; c++) {
            acc[c] += v.x * Ws[(f + 0) * C + c];
            acc[c] += v.y * Ws[(f + 1) * C + c];
            acc[c] += v.z * Ws[(f + 2) * C + c];
            acc[c] += v.w * Ws[(f + 3) * C + c];
        }
    }

    float4* yo = (float4*)(y + (size_t)node * C);
#pragma unroll
    for (int i = 0; i < 8; i++)
        yo[i] = make_float4(acc[4 * i], acc[4 * i + 1], acc[4 * i + 2], acc[4 * i + 3]);
}

// ---------------------------------------------------------------------------
// K2: histogram over 400K (row,slice) keys.
// ---------------------------------------------------------------------------
__global__ __launch_bounds__(256) void hist_rs_k(const int* __restrict__ rows,
                                                 const int* __restrict__ cols,
                                                 int* __restrict__ rs) {
    const int e = blockIdx.x * 256 + threadIdx.x;
    if (e >= NE) return;
    const int key = rows[e] * NSLICE + cols[e] / SLICEW;
    atomicAdd(&rs[key], 1);
}

// ---------------------------------------------------------------------------
// K3a/b/c: hierarchical exclusive scan of rs[400000] -> rs_start[400001].
// ---------------------------------------------------------------------------
__global__ __launch_bounds__(256) void scan1_k(const int* __restrict__ rs,
                                               int* __restrict__ psum) {
    __shared__ int red[256];
    const int base = blockIdx.x * 1024;
    int s = 0;
    for (int i = threadIdx.x; i < 1024; i += 256) {
        const int idx = base + i;
        if (idx < NKEY) s += rs[idx];
    }
    red[threadIdx.x] = s;
    __syncthreads();
    for (int d = 128; d > 0; d >>= 1) {
        if (threadIdx.x < d) red[threadIdx.x] += red[threadIdx.x + d];
        __syncthreads();
    }
    if (threadIdx.x == 0) psum[blockIdx.x] = red[0];
}

__global__ __launch_bounds__(256) void scan2_k(int* __restrict__ psum,
                                               int* __restrict__ rs_start) {
    __shared__ int sA[512], sB[512];
    const int tid = threadIdx.x;
    for (int i = tid; i < 512; i += 256) sA[i] = (i < 391) ? psum[i] : 0;
    __syncthreads();
    int* src = sA;
    int* dst = sB;
    for (int d = 1; d < 512; d <<= 1) {
        for (int i = tid; i < 512; i += 256) {
            int v = src[i];
            if (i >= d) v += src[i - d];
            dst[i] = v;
        }
        __syncthreads();
        int* t = src; src = dst; dst = t;
    }
    for (int i = tid; i < 391; i += 256) psum[i] = (i == 0) ? 0 : src[i - 1];
    if (tid == 0) rs_start[NKEY] = NE;
}

__global__ __launch_bounds__(256) void scan3_k(const int* __restrict__ rs,
                                               const int* __restrict__ psum,
                                               int* __restrict__ rs_start,
                                               int* __restrict__ bcur) {
    __shared__ int sA[1024], sB[1024];
    const int tid = threadIdx.x;
    const int base = blockIdx.x * 1024;
    for (int i = tid; i < 1024; i += 256) {
        const int idx = base + i;
        sA[i] = (idx < NKEY) ? rs[idx] : 0;
    }
    __syncthreads();
    int* src = sA;
    int* dst = sB;
    for (int d = 1; d < 1024; d <<= 1) {
        for (int i = tid; i < 1024; i += 256) {
            int v = src[i];
            if (i >= d) v += src[i - d];
            dst[i] = v;
        }
        __syncthreads();
        int* t = src; src = dst; dst = t;
    }
    const int pb = psum[blockIdx.x];
    for (int i = tid; i < 1024; i += 256) {
        const int idx = base + i;
        if (idx < NKEY) {
            const int st = pb + ((i == 0) ? 0 : src[i - 1]);
            rs_start[idx] = st;
            if ((idx & (KPB - 1)) == 0) bcur[idx >> 9] = st;  // coarse bucket cursor
        }
    }
}

// ---------------------------------------------------------------------------
// K4: part1 — LDS-staged coarse partition (round-3 part_c, proven ~150us).
// bucket = key>>9 == row>>7. Entry: { (key&511)<<17 | col , val*alpha }.
// ---------------------------------------------------------------------------
__global__ __launch_bounds__(256) void part1_k(const float* __restrict__ vals,
                                               const int* __restrict__ rows,
                                               const int* __restrict__ cols,
                                               const float* __restrict__ alpha,
                                               int* __restrict__ bcur,
                                               int2* __restrict__ edgebuf) {
    __shared__ int sA[1024];
    __shared__ int sB[1024];
    __shared__ int lpos[NBUCK];
    __shared__ int lbase[NBUCK];
    __shared__ int2 stage[CHUNK];            // 32 KB
    __shared__ unsigned short sbin[CHUNK];   // 8 KB

    const int tid = threadIdx.x;
    const int base = blockIdx.x * CHUNK;

    for (int i = tid; i < 1024; i += 256) sA[i] = 0;
    __syncthreads();

    int kj[EPT], cj[EPT];
    float wj[EPT];
#pragma unroll
    for (int j = 0; j < EPT; j++) {
        const int e = base + j * 256 + tid;
        if (e < NE) {
            const int r = rows[e];
            cj[j] = cols[e];
            kj[j] = r * NSLICE + cj[j] / SLICEW;
            const int k = (e >= 2 * E) ? 2 : (e >= E) ? 1 : 0;
            wj[j] = vals[e] * alpha[k];
            atomicAdd(&sA[kj[j] >> 9], 1);
        } else {
            kj[j] = -1;
        }
    }
    __syncthreads();

    {   // inclusive block scan of sA[0..1023]
        int* src = sA;
        int* dst = sB;
        for (int d = 1; d < 1024; d <<= 1) {
            for (int i = tid; i < 1024; i += 256) {
                int v = src[i];
                if (i >= d) v += src[i - d];
                dst[i] = v;
            }
            __syncthreads();
            int* t = src; src = dst; dst = t;
        }
    }

    for (int i = tid; i < NBUCK; i += 256) {
        const int excl = (i == 0) ? 0 : sA[i - 1];
        const int cnt = sA[i] - excl;
        lpos[i] = excl;
        if (cnt) lbase[i] = atomicAdd(&bcur[i], cnt);
    }
    __syncthreads();

#pragma unroll
    for (int j = 0; j < EPT; j++) {
        if (kj[j] >= 0) {
            const int b = kj[j] >> 9;
            const int p = atomicAdd(&lpos[b], 1);
            stage[p] = make_int2(((kj[j] & (KPB - 1)) << 17) | cj[j],
                                 __float_as_int(wj[j]));
            sbin[p] = (unsigned short)b;
        }
    }
    __syncthreads();

    const int total = sA[1023];
    for (int p = tid; p < total; p += 256) {
        const int b = sbin[p];
        const int excl = (b == 0) ? 0 : sA[b - 1];
        edgebuf[lbase[b] + (p - excl)] = stage[p];
    }
}

// ---------------------------------------------------------------------------
// K5: part2 — per-bucket in-LDS counting sort to exact rs_start positions.
// In-place: full bucket staged in LDS before any write-back.
// ---------------------------------------------------------------------------
__global__ __launch_bounds__(256) void part2_k(const int* __restrict__ rs_start,
                                               int2* __restrict__ edgebuf) {
    __shared__ int2 sstage[P2CAP];   // 64 KB
    __shared__ int lbin[KPB];        // 2 KB — global write cursors

    const int tid = threadIdx.x;
    const int b = blockIdx.x;
    const int bstart = rs_start[b << 9];
    int endIdx = (b + 1) << 9;
    if (endIdx > NKEY) endIdx = NKEY;
    const int bend = rs_start[endIdx];
    const int n = bend - bstart;
    if (n <= 0) return;
    if (n > P2CAP) return;  // statistically impossible (mean 6144, 26 sigma)

    for (int k = tid; k < KPB; k += 256) {
        const int idx = (b << 9) + k;
        lbin[k] = (idx < NKEY) ? rs_start[idx] : NE;
    }
    for (int i = tid; i < n; i += 256) sstage[i] = edgebuf[bstart + i];
    __syncthreads();

    for (int i = tid; i < n; i += 256) {
        const int2 e = sstage[i];
        const int sub = ((unsigned)e.x) >> 17;
        const int pos = atomicAdd(&lbin[sub], 1);
        edgebuf[pos] = e;
    }
}

// ---------------------------------------------------------------------------
// K6: gather — 32 lanes per (row, slice) task, 8 tasks per block (one slice).
// s = blockIdx&3 -> under round-robin block->XCD mapping each XCD gathers
// from ONE 3.2 MB y-slice (L2-resident). Edge reads nontemporal to protect
// the slice. Partials merged via contiguous 128B atomic bursts; bias on s==0.
// Max occupancy: no LDS, low VGPR, 50K blocks.
// ---------------------------------------------------------------------------
__global__ __launch_bounds__(256) void gathers_k(const long long* __restrict__ eb,
                                                 const int* __restrict__ rs_start,
                                                 const float* __restrict__ y,
                                                 const float* __restrict__ bias,
                                                 float* __restrict__ out) {
    const int blk = blockIdx.x;
    const int s = blk & (NSLICE - 1);
    const int row = (blk >> 2) * 8 + (threadIdx.x >> 5);
    const int c = threadIdx.x & 31;
    const int key = row * NSLICE + s;
    const int st = rs_start[key];
    const int en = rs_start[key + 1];

    float acc = (s == 0) ? bias[c] : 0.f;

    int i = st;
    for (; i + 4 <= en; i += 4) {  // 4 gathers in flight
        const long long l0 = __builtin_nontemporal_load(&eb[i + 0]);
        const long long l1 = __builtin_nontemporal_load(&eb[i + 1]);
        const long long l2 = __builtin_nontemporal_load(&eb[i + 2]);
        const long long l3 = __builtin_nontemporal_load(&eb[i + 3]);
        const float y0 = y[(((int)l0) & 0x1FFFF) * C + c];
        const float y1 = y[(((int)l1) & 0x1FFFF) * C + c];
        const float y2 = y[(((int)l2) & 0x1FFFF) * C + c];
        const float y3 = y[(((int)l3) & 0x1FFFF) * C + c];
        acc += __int_as_float((int)(l0 >> 32)) * y0;
        acc += __int_as_float((int)(l1 >> 32)) * y1;
        acc += __int_as_float((int)(l2 >> 32)) * y2;
        acc += __int_as_float((int)(l3 >> 32)) * y3;
    }
    for (; i < en; i++) {
        const long long l0 = __builtin_nontemporal_load(&eb[i]);
        acc += __int_as_float((int)(l0 >> 32)) * y[(((int)l0) & 0x1FFFF) * C + c];
    }

    unsafeAtomicAdd(out + (size_t)row * C + c, acc);
}

// ---------------------------------------------------------------------------
// Fallback (proven): atomic scatter if workspace too small.
// ---------------------------------------------------------------------------
__global__ __launch_bounds__(256) void scatter_edges(
    const float* __restrict__ vals, const int* __restrict__ rows,
    const int* __restrict__ cols, const float* __restrict__ alpha,
    const float* __restrict__ y, float* __restrict__ out_acc) {
    const int t = blockIdx.x * 256 + threadIdx.x;
    const int e = t >> 5;
    const int c = t & 31;
    if (e >= KH * E) return;
    const int k = (e >= 2 * E) ? 2 : (e >= E) ? 1 : 0;
    const float w = vals[e] * alpha[k];
    const float yv = y[(size_t)cols[e] * C + c];
    unsafeAtomicAdd(out_acc + (size_t)rows[e] * C + c, w * yv);
}

__global__ __launch_bounds__(256) void finalize_k(float* __restrict__ out,
                                                  const float* __restrict__ bias) {
    const int idx = (blockIdx.x * 256 + threadIdx.x) * 4;
    if (idx >= N_NODES * C) return;
    const int c0 = idx & (C - 1);
    float4 v = *(float4*)(out + idx);
    v.x += bias[c0 + 0];
    v.y += bias[c0 + 1];
    v.z += bias[c0 + 2];
    v.w += bias[c0 + 3];
    *(float4*)(out + idx) = v;
}

// ---------------------------------------------------------------------------
extern "C" void kernel_launch(void* const* d_in, const int* in_sizes, int n_in,
                              void* d_out, int out_size, void* d_ws, size_t ws_size,
                              hipStream_t stream) {
    const float* x         = (const float*)d_in[0];
    const float* edge_vals = (const float*)d_in[1];
    const float* W         = (const float*)d_in[2];
    const float* b         = (const float*)d_in[3];
    const float* alpha     = (const float*)d_in[4];
    const int*   edge_rows = (const int*)d_in[5];
    const int*   edge_cols = (const int*)d_in[6];
    float*       out       = (float*)d_out;

    // Workspace layout
    const size_t offY   = 0;                                   // 12,800,000
    const size_t offEB  = (size_t)N_NODES * C * 4;             // 38,400,000
    const size_t offRS  = offEB + (size_t)NE * 8;              // 51,200,000
    const size_t offPS  = offRS + (((size_t)(NKEY + 1) * 4 + 255) & ~(size_t)255);
    const size_t offBC  = offPS + ((391 * 4 + 255) & ~(size_t)255);
    const size_t need   = offBC + (size_t)NBUCK * 4;           // ~52.81 MB

    float* y = (float*)((char*)d_ws + offY);

    gemm_xw<<<(N_NODES + 255) / 256, 256, 0, stream>>>(x, W, y);

    if (ws_size >= need) {
        int2* edgebuf  = (int2*)((char*)d_ws + offEB);
        int*  rs       = (int*)((char*)d_ws + offRS);   // counts, then rs_start
        int*  psum     = (int*)((char*)d_ws + offPS);
        int*  bcur     = (int*)((char*)d_ws + offBC);

        hipMemsetAsync(rs, 0, (size_t)(NKEY + 1) * 4, stream);
        hipMemsetAsync(out, 0, (size_t)N_NODES * C * sizeof(float), stream);

        const int eblocks = (NE + 255) / 256;
        hist_rs_k<<<eblocks, 256, 0, stream>>>(edge_rows, edge_cols, rs);
        scan1_k<<<391, 256, 0, stream>>>(rs, psum);
        scan2_k<<<1, 256, 0, stream>>>(psum, rs);
        scan3_k<<<391, 256, 0, stream>>>(rs, psum, rs, bcur);  // in-place per-block
        part1_k<<<NCHUNK, 256, 0, stream>>>(edge_vals, edge_rows, edge_cols,
                                            alpha, bcur, edgebuf);
        part2_k<<<NBUCK, 256, 0, stream>>>(rs, edgebuf);
        gathers_k<<<(N_NODES / 8) * NSLICE, 256, 0, stream>>>(
            (const long long*)edgebuf, rs, y, b, out);
    } else {
        hipMemsetAsync(out, 0, (size_t)N_NODES * C * sizeof(float), stream);
        const long long scatter_threads = (long long)KH * E * C;
        const int scatter_blocks = (int)((scatter_threads + 255) / 256);
        scatter_edges<<<scatter_blocks, 256, 0, stream>>>(
            edge_vals, edge_rows, edge_cols, alpha, y, out);
        finalize_k<<<(N_NODES * C / 4 + 255) / 256, 256, 0, stream>>>(out, b);
    }
}

// Round 6
// 432.575 us; speedup vs baseline: 5.6416x; 1.3696x over previous
//
#include <hip/hip_runtime.h>

#define N_NODES 100000
#define F 64
#define C 32
#define KH 3
#define E 1600000
#define NE (KH * E)                        // 4,800,000 edges

#define NSLICE 4                           // y col-slices; 3.2 MB < 4 MB L2/XCD
#define SLICEW 25000
#define NKEY (N_NODES * NSLICE)            // 400,000 sort keys (row*4 + slice)
#define KPB 512                            // keys per coarse bucket (= 128 rows)
#define NBUCK ((NKEY + KPB - 1) / KPB)     // 782
#define CHUNK 4096                         // edges per part1/hist block
#define EPT (CHUNK / 256)
#define NCHUNK ((NE + CHUNK - 1) / CHUNK)  // 1172
#define P2CAP 8192                         // part2 LDS capacity (mean 6144, sd 78)

// ---------------------------------------------------------------------------
// K1: y[n, c] = sum_f x[n, f] * W[f, c]
// ---------------------------------------------------------------------------
__global__ __launch_bounds__(256) void gemm_xw(const float* __restrict__ x,
                                               const float* __restrict__ W,
                                               float* __restrict__ y) {
    __shared__ float Ws[F * C];
    for (int i = threadIdx.x; i < F * C; i += 256) Ws[i] = W[i];
    __syncthreads();

    const int node = blockIdx.x * 256 + threadIdx.x;
    if (node >= N_NODES) return;

    const float4* xp = (const float4*)(x + (size_t)node * F);
    float acc[C];
#pragma unroll
    for (int c = 0; c < C; c++) acc[c] = 0.f;

#pragma unroll
    for (int i = 0; i < 16; i++) {
        float4 v = xp[i];
        const int f = i * 4;
#pragma unroll
        for (int c = 0; c < C; c++) {
            acc[c] += v.x * Ws[(f + 0) * C + c];
            acc[c] += v.y * Ws[(f + 1) * C + c];
            acc[c] += v.z * Ws[(f + 2) * C + c];
            acc[c] += v.w * Ws[(f + 3) * C + c];
        }
    }

    float4* yo = (float4*)(y + (size_t)node * C);
#pragma unroll
    for (int i = 0; i < 8; i++)
        yo[i] = make_float4(acc[4 * i], acc[4 * i + 1], acc[4 * i + 2], acc[4 * i + 3]);
}

// ---------------------------------------------------------------------------
// K2: coarse histogram — LDS-aggregated. bucket = row >> 7 (row-only!).
// Replaces the 184us random-atomic 400K-key histogram: writes < 1 MB.
// ---------------------------------------------------------------------------
__global__ __launch_bounds__(256) void hist_c(const int* __restrict__ rows,
                                              int* __restrict__ hcnt) {
    __shared__ int h[NBUCK];
    for (int i = threadIdx.x; i < NBUCK; i += 256) h[i] = 0;
    __syncthreads();
    const int base = blockIdx.x * CHUNK;
#pragma unroll
    for (int j = 0; j < EPT; j++) {
        const int e = base + j * 256 + threadIdx.x;
        if (e < NE) atomicAdd(&h[rows[e] >> 7], 1);
    }
    __syncthreads();
    for (int i = threadIdx.x; i < NBUCK; i += 256) {
        const int c = h[i];
        if (c) atomicAdd(&hcnt[i], c);
    }
}

// ---------------------------------------------------------------------------
// K3: single-block scan of 782 bucket counts -> bstart[0..NBUCK], bcur init,
// plus the rs_start[NKEY] sentinel.
// ---------------------------------------------------------------------------
__global__ __launch_bounds__(256) void scan_c(const int* __restrict__ hcnt,
                                              int* __restrict__ bstart,
                                              int* __restrict__ bcur,
                                              int* __restrict__ rs_start) {
    __shared__ int sA[1024], sB[1024];
    const int tid = threadIdx.x;
    for (int i = tid; i < 1024; i += 256) sA[i] = (i < NBUCK) ? hcnt[i] : 0;
    __syncthreads();
    int* src = sA;
    int* dst = sB;
    for (int d = 1; d < 1024; d <<= 1) {
        for (int i = tid; i < 1024; i += 256) {
            int v = src[i];
            if (i >= d) v += src[i - d];
            dst[i] = v;
        }
        __syncthreads();
        int* t = src; src = dst; dst = t;
    }
    for (int i = tid; i < NBUCK; i += 256) {
        const int excl = (i == 0) ? 0 : src[i - 1];
        bstart[i] = excl;
        bcur[i] = excl;
    }
    if (tid == 0) {
        bstart[NBUCK] = NE;
        rs_start[NKEY] = NE;
    }
}

// ---------------------------------------------------------------------------
// K4: part1 — LDS-staged coarse partition (proven structure).
// bucket = row>>7. Entry: { (key&511)<<17 | col , val*alpha }.
// ---------------------------------------------------------------------------
__global__ __launch_bounds__(256) void part1_k(const float* __restrict__ vals,
                                               const int* __restrict__ rows,
                                               const int* __restrict__ cols,
                                               const float* __restrict__ alpha,
                                               int* __restrict__ bcur,
                                               int2* __restrict__ edgebuf) {
    __shared__ int sA[1024];
    __shared__ int sB[1024];
    __shared__ int lpos[NBUCK];
    __shared__ int lbase[NBUCK];
    __shared__ int2 stage[CHUNK];            // 32 KB
    __shared__ unsigned short sbin[CHUNK];   // 8 KB

    const int tid = threadIdx.x;
    const int base = blockIdx.x * CHUNK;

    for (int i = tid; i < 1024; i += 256) sA[i] = 0;
    __syncthreads();

    int kj[EPT], cj[EPT];
    float wj[EPT];
#pragma unroll
    for (int j = 0; j < EPT; j++) {
        const int e = base + j * 256 + tid;
        if (e < NE) {
            const int r = rows[e];
            cj[j] = cols[e];
            kj[j] = r * NSLICE + cj[j] / SLICEW;
            const int k = (e >= 2 * E) ? 2 : (e >= E) ? 1 : 0;
            wj[j] = vals[e] * alpha[k];
            atomicAdd(&sA[kj[j] >> 9], 1);
        } else {
            kj[j] = -1;
        }
    }
    __syncthreads();

    {   // inclusive block scan of sA[0..1023]
        int* src = sA;
        int* dst = sB;
        for (int d = 1; d < 1024; d <<= 1) {
            for (int i = tid; i < 1024; i += 256) {
                int v = src[i];
                if (i >= d) v += src[i - d];
                dst[i] = v;
            }
            __syncthreads();
            int* t = src; src = dst; dst = t;
        }
    }

    for (int i = tid; i < NBUCK; i += 256) {
        const int excl = (i == 0) ? 0 : sA[i - 1];
        const int cnt = sA[i] - excl;
        lpos[i] = excl;
        if (cnt) lbase[i] = atomicAdd(&bcur[i], cnt);
    }
    __syncthreads();

#pragma unroll
    for (int j = 0; j < EPT; j++) {
        if (kj[j] >= 0) {
            const int b = kj[j] >> 9;
            const int p = atomicAdd(&lpos[b], 1);
            stage[p] = make_int2(((kj[j] & (KPB - 1)) << 17) | cj[j],
                                 __float_as_int(wj[j]));
            sbin[p] = (unsigned short)b;
        }
    }
    __syncthreads();

    const int total = sA[1023];
    for (int p = tid; p < total; p += 256) {
        const int b = sbin[p];
        const int excl = (b == 0) ? 0 : sA[b - 1];
        edgebuf[lbase[b] + (p - excl)] = stage[p];
    }
}

// ---------------------------------------------------------------------------
// K5: part2 — per-bucket in-LDS counting sort. Computes the 512-key
// sub-histogram + scan FROM THE STAGED DATA (no global fine histogram),
// writes rs_start for its keys (coalesced), then scatters entries to exact
// sorted positions in-place.
// ---------------------------------------------------------------------------
__global__ __launch_bounds__(256) void part2_k(const int* __restrict__ bstart,
                                               int* __restrict__ rs_start,
                                               int2* __restrict__ edgebuf) {
    __shared__ int2 sstage[P2CAP];   // 64 KB
    __shared__ int sh[KPB];          // 2 KB  sub-histogram -> scan src
    __shared__ int sg[KPB];          // 2 KB  scan scratch
    __shared__ int lbin[KPB];        // 2 KB  write cursors

    const int tid = threadIdx.x;
    const int b = blockIdx.x;
    const int bs = bstart[b];
    const int be = bstart[b + 1];
    const int n = be - bs;

    for (int k = tid; k < KPB; k += 256) sh[k] = 0;
    __syncthreads();

    if (n <= P2CAP) {
        for (int i = tid; i < n; i += 256) {
            const int2 e = edgebuf[bs + i];
            sstage[i] = e;
            atomicAdd(&sh[((unsigned)e.x) >> 17], 1);
        }
    }
    __syncthreads();

    // inclusive scan of sh[0..511] (ping-pong sh<->sg, 9 rounds -> ends in sg)
    {
        int* src = sh;
        int* dst = sg;
        for (int d = 1; d < KPB; d <<= 1) {
            for (int i = tid; i < KPB; i += 256) {
                int v = src[i];
                if (i >= d) v += src[i - d];
                dst[i] = v;
            }
            __syncthreads();
            int* t = src; src = dst; dst = t;
        }
        // KPB=512 -> 9 rounds (odd) -> result in sg
    }

    // per-key start positions; publish rs_start (coalesced 2KB write)
    for (int k = tid; k < KPB; k += 256) {
        const int st = bs + ((k == 0) ? 0 : sg[k - 1]);
        lbin[k] = st;
        const int idx = (b << 9) + k;
        if (idx < NKEY) rs_start[idx] = st;
    }
    __syncthreads();

    if (n > P2CAP) return;  // statistically impossible (26 sigma)

    for (int i = tid; i < n; i += 256) {
        const int2 e = sstage[i];
        const int sub = ((unsigned)e.x) >> 17;
        const int pos = atomicAdd(&lbin[sub], 1);
        edgebuf[pos] = e;
    }
}

// ---------------------------------------------------------------------------
// K6: gather — 32 lanes per (row, slice) task, 8 tasks per block (one slice).
// s = blockIdx&3 -> under round-robin block->XCD mapping each XCD gathers
// from ONE 3.2 MB y-slice (L2-resident). Edge reads nontemporal.
// Partials merged via contiguous atomic bursts; bias on s==0.
// ---------------------------------------------------------------------------
__global__ __launch_bounds__(256) void gathers_k(const long long* __restrict__ eb,
                                                 const int* __restrict__ rs_start,
                                                 const float* __restrict__ y,
                                                 const float* __restrict__ bias,
                                                 float* __restrict__ out) {
    const int blk = blockIdx.x;
    const int s = blk & (NSLICE - 1);
    const int row = (blk >> 2) * 8 + (threadIdx.x >> 5);
    const int c = threadIdx.x & 31;
    const int key = row * NSLICE + s;
    const int st = rs_start[key];
    const int en = rs_start[key + 1];

    float acc = (s == 0) ? bias[c] : 0.f;

    int i = st;
    for (; i + 4 <= en; i += 4) {  // 4 gathers in flight
        const long long l0 = __builtin_nontemporal_load(&eb[i + 0]);
        const long long l1 = __builtin_nontemporal_load(&eb[i + 1]);
        const long long l2 = __builtin_nontemporal_load(&eb[i + 2]);
        const long long l3 = __builtin_nontemporal_load(&eb[i + 3]);
        const float y0 = y[(((int)l0) & 0x1FFFF) * C + c];
        const float y1 = y[(((int)l1) & 0x1FFFF) * C + c];
        const float y2 = y[(((int)l2) & 0x1FFFF) * C + c];
        const float y3 = y[(((int)l3) & 0x1FFFF) * C + c];
        acc += __int_as_float((int)(l0 >> 32)) * y0;
        acc += __int_as_float((int)(l1 >> 32)) * y1;
        acc += __int_as_float((int)(l2 >> 32)) * y2;
        acc += __int_as_float((int)(l3 >> 32)) * y3;
    }
    for (; i < en; i++) {
        const long long l0 = __builtin_nontemporal_load(&eb[i]);
        acc += __int_as_float((int)(l0 >> 32)) * y[(((int)l0) & 0x1FFFF) * C + c];
    }

    unsafeAtomicAdd(out + (size_t)row * C + c, acc);
}

// ---------------------------------------------------------------------------
// Fallback (proven): atomic scatter if workspace too small.
// ---------------------------------------------------------------------------
__global__ __launch_bounds__(256) void scatter_edges(
    const float* __restrict__ vals, const int* __restrict__ rows,
    const int* __restrict__ cols, const float* __restrict__ alpha,
    const float* __restrict__ y, float* __restrict__ out_acc) {
    const int t = blockIdx.x * 256 + threadIdx.x;
    const int e = t >> 5;
    const int c = t & 31;
    if (e >= KH * E) return;
    const int k = (e >= 2 * E) ? 2 : (e >= E) ? 1 : 0;
    const float w = vals[e] * alpha[k];
    const float yv = y[(size_t)cols[e] * C + c];
    unsafeAtomicAdd(out_acc + (size_t)rows[e] * C + c, w * yv);
}

__global__ __launch_bounds__(256) void finalize_k(float* __restrict__ out,
                                                  const float* __restrict__ bias) {
    const int idx = (blockIdx.x * 256 + threadIdx.x) * 4;
    if (idx >= N_NODES * C) return;
    const int c0 = idx & (C - 1);
    float4 v = *(float4*)(out + idx);
    v.x += bias[c0 + 0];
    v.y += bias[c0 + 1];
    v.z += bias[c0 + 2];
    v.w += bias[c0 + 3];
    *(float4*)(out + idx) = v;
}

// ---------------------------------------------------------------------------
extern "C" void kernel_launch(void* const* d_in, const int* in_sizes, int n_in,
                              void* d_out, int out_size, void* d_ws, size_t ws_size,
                              hipStream_t stream) {
    const float* x         = (const float*)d_in[0];
    const float* edge_vals = (const float*)d_in[1];
    const float* W         = (const float*)d_in[2];
    const float* b         = (const float*)d_in[3];
    const float* alpha     = (const float*)d_in[4];
    const int*   edge_rows = (const int*)d_in[5];
    const int*   edge_cols = (const int*)d_in[6];
    float*       out       = (float*)d_out;

    // Workspace layout
    const size_t offY   = 0;                                   // 12,800,000
    const size_t offEB  = (size_t)N_NODES * C * 4;             // 38,400,000
    const size_t offRS  = offEB + (size_t)NE * 8;              // 51,200,000
    const size_t offBS  = offRS + (((size_t)(NKEY + 1) * 4 + 255) & ~(size_t)255);
    const size_t offBC  = offBS + (((NBUCK + 1) * 4 + 255) & ~(size_t)255);
    const size_t offHC  = offBC + ((NBUCK * 4 + 255) & ~(size_t)255);
    const size_t need   = offHC + (size_t)NBUCK * 4;           // ~52.81 MB

    float* y = (float*)((char*)d_ws + offY);

    gemm_xw<<<(N_NODES + 255) / 256, 256, 0, stream>>>(x, W, y);

    if (ws_size >= need) {
        int2* edgebuf  = (int2*)((char*)d_ws + offEB);
        int*  rs_start = (int*)((char*)d_ws + offRS);
        int*  bstart   = (int*)((char*)d_ws + offBS);
        int*  bcur     = (int*)((char*)d_ws + offBC);
        int*  hcnt     = (int*)((char*)d_ws + offHC);

        hipMemsetAsync(hcnt, 0, (size_t)NBUCK * 4, stream);
        hipMemsetAsync(out, 0, (size_t)N_NODES * C * sizeof(float), stream);

        hist_c<<<NCHUNK, 256, 0, stream>>>(edge_rows, hcnt);
        scan_c<<<1, 256, 0, stream>>>(hcnt, bstart, bcur, rs_start);
        part1_k<<<NCHUNK, 256, 0, stream>>>(edge_vals, edge_rows, edge_cols,
                                            alpha, bcur, edgebuf);
        part2_k<<<NBUCK, 256, 0, stream>>>(bstart, rs_start, edgebuf);
        gathers_k<<<(N_NODES / 8) * NSLICE, 256, 0, stream>>>(
            (const long long*)edgebuf, rs_start, y, b, out);
    } else {
        hipMemsetAsync(out, 0, (size_t)N_NODES * C * sizeof(float), stream);
        const long long scatter_threads = (long long)KH * E * C;
        const int scatter_blocks = (int)((scatter_threads + 255) / 256);
        scatter_edges<<<scatter_blocks, 256, 0, stream>>>(
            edge_vals, edge_rows, edge_cols, alpha, y, out);
        finalize_k<<<(N_NODES * C / 4 + 255) / 256, 256, 0, stream>>>(out, b);
    }
}